// Round 7
// baseline (314.044 us; speedup 1.0000x reference)
//
#include <hip/hip_runtime.h>
#include <hip/hip_bf16.h>
#include <stdint.h>
#include <stddef.h>

typedef __attribute__((ext_vector_type(4))) float f32x4;
typedef _Float16 f16x8 __attribute__((ext_vector_type(8)));

#define BN 128
// coarse scores are in 2^20-scaled units: sc = 2^20*(||e||^2 - 2 z.e) + eps.
#define MARGIN 230.0f

// ---------------------------------------------------------------------------
// emb f32 [1024,256] -> fp16 (e*1024) in ws, AND enorm[k] = sum((f32)e'_kd^2)
// one wave per code: block b, wave w -> code b*4+w; lane l -> dims l*4..+4
// ---------------------------------------------------------------------------
__global__ __launch_bounds__(256) void emb_prep_kernel(const float* __restrict__ emb,
                                                       _Float16* __restrict__ embf,
                                                       float* __restrict__ enorm) {
    int t = threadIdx.x, w = t >> 6, l = t & 63;
    int code = blockIdx.x * 4 + w;
    float s = 0.f;
#pragma unroll
    for (int j = 0; j < 4; ++j) {
        int k = code * 256 + l * 4 + j;
        _Float16 h = (_Float16)(emb[k] * 1024.0f);   // *2^10 exact, RNE cvt
        embf[k] = h;
        float f = (float)h;
        s = fmaf(f, f, s);
    }
#pragma unroll
    for (int off = 1; off < 64; off <<= 1) s += __shfl_xor(s, off, 64);
    if (l == 0) enorm[code] = s;                      // 2^20 * ||e'||^2
}

// ---------------------------------------------------------------------------
// Fused VQ: fp16 MFMA coarse pass (B streamed from L2, A from LDS, no K-loop
// barriers) + wave-cooperative bit-exact numpy-f32 rescore of near-ties.
// ---------------------------------------------------------------------------
__global__ __launch_bounds__(256, 2) void vq_kernel(
        const float* __restrict__ z,
        const float* __restrict__ emb,
        const _Float16* __restrict__ embf,
        const float* __restrict__ enorm,
        float* __restrict__ out) {

    __shared__ _Float16 A_sh[BN * 256];   // 64 KB fp16 z tile (read-only post-stage)
    __shared__ int      W_sh[1440];       // worklist + idx_fin (5.8 KB)

    const int t  = threadIdx.x;
    const int w  = t >> 6;
    const int l  = t & 63;
    const int c  = l & 15;   // MFMA N-lane
    const int q  = l >> 4;   // MFMA quad
    const int wr = w >> 1;   // spatial half
    const int wc = w & 1;    // code half

    const int n0    = blockIdx.x * BN;
    const int b_img = n0 >> 12;
    const int hw0   = n0 & 4095;
    const float* zb = z + (size_t)b_img * (256 * 4096) + hw0;

    // ---- Stage A: z NCHW f32 -> fp16 [n][d], transposed, swizzled ----
#pragma unroll
    for (int it = 0; it < 4; ++it) {
        int task = it * 256 + t;      // 32 nquad x 32 dgroups
        int nq = task & 31;           // lane-contiguous -> 512B coalesced
        int dg = task >> 5;
        const float* g = zb + (size_t)(dg * 8) * 4096 + nq * 4;
        f32x4 col[8];
#pragma unroll
        for (int j = 0; j < 8; ++j) col[j] = *(const f32x4*)(g + (size_t)j * 4096);
#pragma unroll
        for (int u = 0; u < 4; ++u) {
            int n = nq * 4 + u;
            f16x8 v;
#pragma unroll
            for (int j = 0; j < 8; ++j) v[j] = (_Float16)col[j][u];
            *(f16x8*)&A_sh[n * 256 + ((dg ^ (n & 7)) * 8)] = v;
        }
    }
    __syncthreads();    // the ONLY barrier before the K-loop ends

    f32x4 acc[4][4];
    float v1[16], v2[16];
    int   i1[16], i2[16];
#pragma unroll
    for (int p = 0; p < 16; ++p) { v1[p] = 3.4e38f; v2[p] = 3.4e38f; i1[p] = 0x7fffffff; i2[p] = 0x7fffffff; }

    // per-wave B base: code (wc*64 + c), dim q*8
    const _Float16* bbase = embf + ((size_t)(wc * 64 + c) << 8) + q * 8;

    for (int kt = 0; kt < 8; ++kt) {
        // enorm for this kt's 4 code-fragments (L1/L2-hot, hoisted above steps)
        float en_j[4];
#pragma unroll
        for (int j = 0; j < 4; ++j)
            en_j[j] = enorm[kt * 128 + wc * 64 + j * 16 + c];

#pragma unroll
        for (int i = 0; i < 4; ++i)
#pragma unroll
            for (int j = 0; j < 4; ++j) acc[i][j] = (f32x4){0.f, 0.f, 0.f, 0.f};

#pragma unroll
        for (int ds = 0; ds < 8; ++ds) {
            f16x8 af[4], bfr[4];
#pragma unroll
            for (int j = 0; j < 4; ++j)
                bfr[j] = *(const f16x8*)(bbase + (((size_t)(kt * 128 + j * 16)) << 8) + ds * 32);
#pragma unroll
            for (int i = 0; i < 4; ++i) {
                int n  = wr * 64 + i * 16 + c;
                int pg = ((ds << 2) + q) ^ (n & 7);
                af[i] = *(const f16x8*)&A_sh[n * 256 + pg * 8];
            }
#pragma unroll
            for (int i = 0; i < 4; ++i)
#pragma unroll
                for (int j = 0; j < 4; ++j)
                    acc[i][j] = __builtin_amdgcn_mfma_f32_16x16x32_f16(af[i], bfr[j], acc[i][j], 0, 0, 0);
        }

        // ---- kt epilogue: sc = en - 2048*acc = 2^20*(||e||^2 - 2 z.e), best-2
#pragma unroll
        for (int j = 0; j < 4; ++j) {
            int code = kt * 128 + wc * 64 + j * 16 + c;
            float en = en_j[j];
#pragma unroll
            for (int i = 0; i < 4; ++i) {
#pragma unroll
                for (int r = 0; r < 4; ++r) {
                    int p = i * 4 + r;
                    float sc = fmaf(-2048.0f, acc[i][j][r], en);
                    if (sc < v1[p]) {
                        v2[p] = v1[p]; i2[p] = i1[p];
                        v1[p] = sc;    i1[p] = code;
                    } else if (sc < v2[p]) {
                        v2[p] = sc;    i2[p] = code;
                    }
                }
            }
        }
    }

    __syncthreads();   // A_sh dead -> reuse as scan scratch

    // ---- dump best-2, diagonal-swizzled: entry(slot,row) at
    //      [slot*128 + ((row+slot)&127)] -> scan reads stride-1, writes <=2-way
    float* cv = (float*)A_sh;              // 64 slots x 128 rows (32 KB)
    int*   ci = ((int*)A_sh) + 8192;       // 32 KB
    int* idx_fin = W_sh;                   // 128
    int* wl_n    = W_sh + 128;             // 1
    int* wl_row  = W_sh + 129;             // 128
    int* wl_nc   = W_sh + 257;             // 128
    int* wl_cand = W_sh + 385;             // 128*8

    if (t == 0) wl_n[0] = 0;
#pragma unroll
    for (int p = 0; p < 16; ++p) {
        int row = wr * 64 + (p >> 2) * 16 + q * 4 + (p & 3);
        int s0  = (wc * 16 + c) * 2;
        cv[s0 * 128       + ((row + s0)     & 127)] = v1[p];
        ci[s0 * 128       + ((row + s0)     & 127)] = i1[p];
        cv[(s0 + 1) * 128 + ((row + s0 + 1) & 127)] = v2[p];
        ci[(s0 + 1) * 128 + ((row + s0 + 1) & 127)] = i2[p];
    }
    __syncthreads();

    if (t < BN) {
        float mv = 3.4e38f; int mi = 0x7fffffff;
#pragma unroll 8
        for (int s = 0; s < 64; ++s) {
            float v = cv[s * 128 + ((t + s) & 127)];
            int  id = ci[s * 128 + ((t + s) & 127)];
            if (v < mv || (v == mv && id < mi)) { mv = v; mi = id; }
        }
        int   cand[8]; int nc = 0;
        float thr = mv + MARGIN;
        for (int s = 0; s < 64; ++s) {
            float v = cv[s * 128 + ((t + s) & 127)];
            int  id = ci[s * 128 + ((t + s) & 127)];
            if (v <= thr && id < 1024 && nc < 8) cand[nc++] = id;
        }
        idx_fin[t] = mi;
        if (nc > 1) {
            int slot = atomicAdd(wl_n, 1);
            wl_row[slot] = t;
            wl_nc[slot]  = nc;
            for (int i = 0; i < nc; ++i) wl_cand[slot * 8 + i] = cand[i];
        }
    }
    __syncthreads();

    // ---- wave-cooperative bit-exact numpy-f32 rescore ----
    int nwl = wl_n[0];
    for (int e = w; e < nwl; e += 4) {
        int row = wl_row[e];
        int nc  = wl_nc[e];
        const float* zrow = zb + row;      // element d at zrow[d*4096]

        // a_n: np pairwise sum of z^2, 16 parallel chains (np 8-acc x 2 halves)
        int j  = l & 15, h = j >> 3, jj = j & 7;
        float x0 = zrow[(size_t)(h * 128 + jj) * 4096];
        float r  = __fmul_rn(x0, x0);
        for (int m = 1; m < 16; ++m) {
            float x = zrow[(size_t)(h * 128 + jj + 8 * m) * 4096];
            r = __fadd_rn(r, __fmul_rn(x, x));
        }
        float s1 = __fadd_rn(r,  __shfl_xor(r,  1, 64));
        float s2 = __fadd_rn(s1, __shfl_xor(s1, 2, 64));
        float s4 = __fadd_rn(s2, __shfl_xor(s2, 4, 64));
        float a_n = __fadd_rn(s4, __shfl_xor(s4, 8, 64));
        a_n = __shfl(a_n, 0, 64);

        float best = 3.4e38f; int bid = 0x7fffffff;
        for (int cx = 0; cx < nc; ++cx) {
            int id = wl_cand[e * 8 + cx];
            const float* er = emb + (size_t)id * 256;
            // b_k: same bit-exact np tree, contiguous reads
            float y0 = er[h * 128 + jj];
            float rb = __fmul_rn(y0, y0);
            for (int m = 1; m < 16; ++m) {
                float y = er[h * 128 + jj + 8 * m];
                rb = __fadd_rn(rb, __fmul_rn(y, y));
            }
            float b1 = __fadd_rn(rb, __shfl_xor(rb, 1, 64));
            float b2 = __fadd_rn(b1, __shfl_xor(b1, 2, 64));
            float b4 = __fadd_rn(b2, __shfl_xor(b2, 4, 64));
            float b_k = __fadd_rn(b4, __shfl_xor(b4, 8, 64));
            b_k = __shfl(b_k, 0, 64);
            // c: f64 dot, 64-lane butterfly (order-free, ~exact)
            double cd = 0.0;
#pragma unroll
            for (int u = 0; u < 4; ++u) {
                int d = l + u * 64;
                cd = fma((double)zrow[(size_t)d * 4096], (double)er[d], cd);
            }
#pragma unroll
            for (int off = 1; off < 64; off <<= 1) cd += __shfl_xor(cd, off, 64);
            float c32 = (float)cd;
            float sc  = __fsub_rn(__fadd_rn(a_n, b_k), __fmul_rn(2.0f, c32));
            if (sc < best || (sc == best && id < bid)) { best = sc; bid = id; }
        }
        if (l == 0) idx_fin[row] = bid;
    }
    __syncthreads();

    // ---- final index write + z_q gather, coalesced NCHW ----
    if (t < BN) out[n0 + t] = (float)idx_fin[t];

    float* zq = out + 65536 + (size_t)b_img * (256 * 4096) + hw0;
#pragma unroll 2
    for (int it = 0; it < 32; ++it) {
        int task = it * 256 + t;   // 256 d x 32 quads
        int d = task >> 5;
        int o = task & 31;         // lane-contiguous -> coalesced stores
        f32x4 v;
#pragma unroll
        for (int jj2 = 0; jj2 < 4; ++jj2) {
            int id = idx_fin[o * 4 + jj2];
            v[jj2] = emb[(size_t)id * 256 + d];
        }
        *(f32x4*)&zq[(size_t)d * 4096 + o * 4] = v;
    }
}

// ---------------------------------------------------------------------------
extern "C" void kernel_launch(void* const* d_in, const int* in_sizes, int n_in,
                              void* d_out, int out_size, void* d_ws, size_t ws_size,
                              hipStream_t stream) {
    const float* z   = (const float*)d_in[0];   // f32 [16,256,64,64]
    const float* emb = (const float*)d_in[1];   // f32 [1024,256]
    _Float16* embf  = (_Float16*)d_ws;                       // 512 KB fp16 (e*1024)
    float*    enorm = (float*)((char*)d_ws + 512 * 1024);    // 4 KB, 2^20*||e'||^2
    float* out = (float*)d_out;

    emb_prep_kernel<<<256, 256, 0, stream>>>(emb, embf, enorm);
    vq_kernel<<<65536 / BN, 256, 0, stream>>>(z, emb, embf, enorm, out);
}